// Round 1
// baseline (1459.403 us; speedup 1.0000x reference)
//
#include <hip/hip_runtime.h>
#include <math.h>

// NPTransitionPrior: B=64, T=514, D=32, H=128, LAGS=2, IN=65
// out layout (fp32): residuals (64*512*32) | sumlogdet (64) | hist_jac (32*32768*64)

namespace {
constexpr int T   = 514;
constexpr int D   = 32;
constexpr int H   = 128;
constexpr int NP  = 512;   // windows per batch (T - LAGS)
constexpr int TN  = 32;    // n-tile per block
constexpr int XR  = 36;    // padded x-row stride (32 + 4, keeps float4 alignment)
constexpr int W1R = 68;    // padded W1 row stride (65 + 3, keeps float4 alignment)
constexpr int GR  = 132;   // padded g row stride (128 + 4)

constexpr int OFF_XROW = 0;                          // (TN+2)*XR = 34*36 = 1224
constexpr int OFF_W1   = OFF_XROW + (TN + 2) * XR;   // 1224   (8704 floats)
constexpr int OFF_G    = OFF_W1 + H * W1R;           // 9928   (4224 floats)
constexpr int OFF_RESP = OFF_G + TN * GR;            // 14152  (256)
constexpr int OFF_JACP = OFF_RESP + 8 * TN;          // 14408  (256)
constexpr int OFF_B1   = OFF_JACP + 8 * TN;          // 14664  (128)
constexpr int OFF_W2   = OFF_B1 + H;                 // 14792  (128)
constexpr int LDS_FLOATS = OFF_W2 + H;               // 14920 floats = 59680 B

constexpr size_t OUT1_OFF = (size_t)64 * NP * D;     // 1048576
constexpr size_t OUT2_OFF = OUT1_OFF + 64;           // 1048640
}

__global__ __launch_bounds__(256, 2) void np_prior_kernel(
    const float* __restrict__ x,    // (64, 514, 32)
    const float* __restrict__ W1,   // (32, 128, 65)
    const float* __restrict__ b1,   // (32, 128)
    const float* __restrict__ W2,   // (32, 128)
    const float* __restrict__ b2,   // (32,)
    float* __restrict__ out)
{
    extern __shared__ float lds[];
    const int tile = blockIdx.x;      // 0..1023  (16 tiles per batch)
    const int d    = blockIdx.y;      // 0..31
    const int b    = tile >> 4;
    const int t0   = (tile & 15) << 5;
    const int tid  = threadIdx.x;

    float* xrow = lds + OFF_XROW;
    float* w1L  = lds + OFF_W1;
    float* gL   = lds + OFF_G;
    float* resP = lds + OFF_RESP;
    float* jacP = lds + OFF_JACP;
    float* b1r  = lds + OFF_B1;
    float* w2r  = lds + OFF_W2;

    // ---- stage global -> LDS (coalesced) ----
    {
        const float* xsrc = x + (size_t)(b * T + t0) * D;
        for (int e = tid; e < (TN + 2) * D; e += 256) {
            int r = e >> 5, c = e & 31;
            xrow[r * XR + c] = xsrc[e];
        }
        const float* w1src = W1 + (size_t)d * H * 65;
        for (int e = tid; e < H * 65; e += 256) {
            int h = e / 65, k = e - h * 65;
            w1L[h * W1R + k] = w1src[e];
        }
        if (tid < H) {
            b1r[tid] = b1[d * H + tid];
            w2r[tid] = W2[d * H + tid];
        }
    }
    __syncthreads();

    // ---- phase 1: pre / act / g.  lane owns n, thread-group owns 16 h's ----
    const int n  = tid & 31;        // window within tile
    const int hg = tid >> 5;        // 0..7, h range [hg*16, hg*16+16)

    // window of 64 history values in registers (constant-indexed after unroll)
    float xx[64];
    #pragma unroll
    for (int j = 0; j < 2; ++j) {
        #pragma unroll
        for (int c = 0; c < 32; c += 4) {
            float4 q = *(const float4*)&xrow[(n + j) * XR + c];
            xx[j * 32 + c + 0] = q.x;
            xx[j * 32 + c + 1] = q.y;
            xx[j * 32 + c + 2] = q.z;
            xx[j * 32 + c + 3] = q.w;
        }
    }
    const float yy = xrow[(n + 2) * XR + d];

    float res = 0.f, jac64 = 0.f;
    const int h0 = hg * 16;
    for (int h = h0; h < h0 + 16; ++h) {
        const float* wrow = &w1L[h * W1R];
        float p0 = b1r[h], p1 = 0.f, p2 = 0.f, p3 = 0.f;
        #pragma unroll
        for (int k = 0; k < 64; k += 4) {
            float4 wq = *(const float4*)(wrow + k);
            p0 += xx[k + 0] * wq.x;
            p1 += xx[k + 1] * wq.y;
            p2 += xx[k + 2] * wq.z;
            p3 += xx[k + 3] * wq.w;
        }
        const float w64 = wrow[64];
        const float pre = (p0 + p1) + (p2 + p3) + yy * w64;
        const float dact = pre >= 0.f ? 1.0f : 0.01f;
        const float g = dact * w2r[h];
        res   += pre * g;            // act*W2 == pre*dact*W2
        jac64 += g * w64;
        gL[n * GR + h] = g;
    }
    resP[hg * TN + n] = res;
    jacP[hg * TN + n] = jac64;
    __syncthreads();

    // ---- phase 2: jac[n][k] for k<64; lane owns k, 8 n's per thread ----
    const int k  = tid & 63;
    const int ng = tid >> 6;        // 0..3 ; n = ng + 4*i, i in 0..7
    float acc[8];
    #pragma unroll
    for (int i = 0; i < 8; ++i) acc[i] = 0.f;

    for (int h = 0; h < H; h += 4) {
        const float wa = w1L[(h + 0) * W1R + k];
        const float wb = w1L[(h + 1) * W1R + k];
        const float wc = w1L[(h + 2) * W1R + k];
        const float wd = w1L[(h + 3) * W1R + k];
        #pragma unroll
        for (int i = 0; i < 8; ++i) {
            const float4 gq = *(const float4*)&gL[(ng + 4 * i) * GR + h];
            acc[i] += gq.x * wa + gq.y * wb + gq.z * wc + gq.w * wd;
        }
    }
    {
        float* out2 = out + OUT2_OFF + (size_t)d * ((size_t)32768 * 64);
        #pragma unroll
        for (int i = 0; i < 8; ++i) {
            const int nn = ng + 4 * i;
            out2[(size_t)(b * NP + t0 + nn) * 64 + k] = acc[i];
        }
    }

    // ---- phase 1b: residuals + logabsdet (threads 0..31) ----
    if (tid < 64) {
        float lg = 0.f;
        if (tid < TN) {
            const int nn = tid;
            float r = b2[d];
            float j = 0.f;
            #pragma unroll
            for (int jj = 0; jj < 8; ++jj) {
                r += resP[jj * TN + nn];
                j += jacP[jj * TN + nn];
            }
            out[(size_t)(b * NP + t0 + nn) * D + d] = r;
            lg = logf(fabsf(j));
        }
        // reduce lg over lanes 0..31 (lanes 32..63 contribute 0)
        #pragma unroll
        for (int off = 32; off > 0; off >>= 1)
            lg += __shfl_down(lg, off, 64);
        if (tid == 0) atomicAdd(out + OUT1_OFF + b, lg);
    }
}

extern "C" void kernel_launch(void* const* d_in, const int* in_sizes, int n_in,
                              void* d_out, int out_size, void* d_ws, size_t ws_size,
                              hipStream_t stream) {
    const float* x  = (const float*)d_in[0];
    const float* W1 = (const float*)d_in[1];
    const float* b1 = (const float*)d_in[2];
    const float* W2 = (const float*)d_in[3];
    const float* b2 = (const float*)d_in[4];
    float* out = (float*)d_out;

    // zero the atomically-accumulated sumlogdet region (64 floats)
    hipMemsetAsync(out + OUT1_OFF, 0, 64 * sizeof(float), stream);

    dim3 grid(1024, 32, 1);
    dim3 block(256, 1, 1);
    hipLaunchKernelGGL(np_prior_kernel, grid, block, LDS_FLOATS * sizeof(float), stream,
                       x, W1, b1, W2, b2, out);
}

// Round 2
// 408.970 us; speedup vs baseline: 3.5685x; 3.5685x over previous
//
#include <hip/hip_runtime.h>
#include <math.h>

// NPTransitionPrior: B=64, T=514, D=32, H=128, LAGS=2, IN=65
// out (fp32): residuals (64*512*32) | sumlogdet (64) | hist_jac (32*32768*64)
//
// Strategy: per block (d, 64-window tile):
//   phase1: pre[h,n] = W1[d] . xx^T via mfma_f32_16x16x32_f16, f16 hi/lo split
//           (3 products: hh -> accP ; h*lo + lo*h -> accQ, pre = accP + accQ/4096)
//           -> noise ~4e-7 (fp32-equivalent) so sign(pre) decisions match fp32.
//   phase2: jac[n,k<64] = g . W1 via plain f16-hi MFMA (linear, 2% threshold).
//   residual / jac64 / logdet in fp32 from MFMA accumulators.

typedef _Float16 f16;
typedef __attribute__((ext_vector_type(8))) _Float16 half8;
typedef __attribute__((ext_vector_type(4))) _Float16 half4;
typedef __attribute__((ext_vector_type(4))) float floatx4;

namespace {
// ---- workspace layout (bytes) ----
constexpr int    XS_ROW   = 40;                                // f16 per padded x row (32+8)
constexpr size_t XS_SPLIT = (size_t)64 * 514 * XS_ROW * 2;     // 2,631,680
constexpr size_t WS_XS_HI = 0;
constexpr size_t WS_XS_LO = XS_SPLIT;
constexpr int    W1_KP    = 72;                                // padded K for W1 (64+8)
constexpr size_t W1_SPLIT = (size_t)32 * 128 * W1_KP * 2;      // 589,824
constexpr size_t WS_W1_HI = 2 * XS_SPLIT;                      // 5,263,360
constexpr size_t WS_W1_LO = WS_W1_HI + W1_SPLIT;
constexpr int    W1T_HP   = 136;                               // padded H for W1T (128+8)
constexpr size_t WS_W1T   = WS_W1_LO + W1_SPLIT;               // 6,443,008
// total ws need: WS_W1T + 32*64*136*2 = 7,000,064 bytes

// ---- LDS layout (bytes) ----
constexpr int L_W1HI = 0;          // 128*72*2 = 18432   (phase 1)
constexpr int L_W1LO = 18432;      // ends 36864         (phase 1)
constexpr int L_GB   = 0;          // 64*136*2 = 17408   (phase 2 overlay)
constexpr int L_W1T  = 17408;      // +17408 = 34816     (phase 2 overlay)
constexpr int L_XSHI = 36864;      // 66*40*2 = 5280
constexpr int L_XSLO = 42144;      // ends 47424
constexpr int L_B1   = 47424;      // 128 f32
constexpr int L_W2   = L_B1 + 512;
constexpr int L_W64  = L_W2 + 512;
constexpr int L_YY   = L_W64 + 512;   // 64 f32
constexpr int L_RES  = L_YY + 256;    // 4*64 f32
constexpr int L_JAC  = L_RES + 1024;
constexpr int L_TOTAL = L_JAC + 1024; // 51264 bytes -> 3 blocks/CU

constexpr size_t OUT1_OFF = (size_t)64 * 512 * 32;   // 1048576
constexpr size_t OUT2_OFF = OUT1_OFF + 64;
}

// ---- split x into f16 hi + (lo*4096), padded rows of 40 ----
__global__ __launch_bounds__(256) void split_x_kernel(
    const float* __restrict__ x, f16* __restrict__ xh, f16* __restrict__ xl)
{
    int idx = blockIdx.x * 256 + threadIdx.x;
    if (idx >= 64 * 514 * 32) return;
    int row = idx >> 5, c = idx & 31;
    float v = x[idx];
    f16 hi = (f16)v;
    float r = v - (float)hi;
    xh[row * XS_ROW + c] = hi;
    xl[row * XS_ROW + c] = (f16)(r * 4096.0f);
}

// ---- split W1[:, :, :64] into fragment layouts ----
__global__ __launch_bounds__(256) void split_w1_kernel(
    const float* __restrict__ W1, f16* __restrict__ wh, f16* __restrict__ wl,
    f16* __restrict__ wT)
{
    int idx = blockIdx.x * 256 + threadIdx.x;
    if (idx >= 32 * 128 * 64) return;
    int d = idx >> 13, rem = idx & 8191;
    int h = rem >> 6, k = rem & 63;
    float v = W1[((size_t)(d * 128 + h)) * 65 + k];
    f16 hi = (f16)v;
    float r = v - (float)hi;
    wh[(size_t)(d * 128 + h) * W1_KP + k] = hi;
    wl[(size_t)(d * 128 + h) * W1_KP + k] = (f16)(r * 4096.0f);
    wT[(size_t)(d * 64 + k) * W1T_HP + h] = hi;   // transposed, hi only (phase 2)
}

__global__ __launch_bounds__(256, 3) void np_main_kernel(
    const float* __restrict__ x,    // (64,514,32)
    const float* __restrict__ W1,   // (32,128,65)
    const float* __restrict__ b1,   // (32,128)
    const float* __restrict__ W2,   // (32,128)
    const float* __restrict__ b2,   // (32,)
    const char* __restrict__ ws,
    float* __restrict__ out)
{
    extern __shared__ char smem[];
    const int tile = blockIdx.x;          // 0..511
    const int d    = blockIdx.y;          // 0..31
    const int b    = tile >> 3;
    const int t0   = (tile & 7) << 6;     // 64-window tile
    const int tid  = threadIdx.x;
    const int wave = tid >> 6, lane = tid & 63;
    const int c = lane & 15, q = lane >> 4;

    float* b1L  = (float*)(smem + L_B1);
    float* W2L  = (float*)(smem + L_W2);
    float* w64L = (float*)(smem + L_W64);
    float* yyL  = (float*)(smem + L_YY);
    float* resP = (float*)(smem + L_RES);
    float* jacP = (float*)(smem + L_JAC);

    // ---------- stage (linear float4 copies from pre-split ws) ----------
    {
        const float4* s1 = (const float4*)(ws + WS_W1_HI + (size_t)d * 18432);
        const float4* s2 = (const float4*)(ws + WS_W1_LO + (size_t)d * 18432);
        float4* d1 = (float4*)(smem + L_W1HI);
        float4* d2 = (float4*)(smem + L_W1LO);
        for (int i = tid; i < 1152; i += 256) { d1[i] = s1[i]; d2[i] = s2[i]; }
        const float4* s3 = (const float4*)(ws + WS_XS_HI + (size_t)(b * 514 + t0) * (XS_ROW * 2));
        const float4* s4 = (const float4*)(ws + WS_XS_LO + (size_t)(b * 514 + t0) * (XS_ROW * 2));
        float4* d3 = (float4*)(smem + L_XSHI);
        float4* d4 = (float4*)(smem + L_XSLO);
        for (int i = tid; i < 330; i += 256) { d3[i] = s3[i]; d4[i] = s4[i]; }
        if (tid < 128) {
            b1L[tid]  = b1[d * 128 + tid];
            W2L[tid]  = W2[d * 128 + tid];
            w64L[tid] = W1[(size_t)(d * 128 + tid) * 65 + 64];
        }
        if (tid < 64) yyL[tid] = x[(size_t)(b * 514 + t0 + tid + 2) * 32 + d];
    }
    __syncthreads();

    // ---------- phase 1: pre[h,n], M=h(wave owns 32), N=n(all 64), K=64 ----------
    floatx4 accP[2][4], accQ[2][4];
    #pragma unroll
    for (int ht = 0; ht < 2; ++ht)
        #pragma unroll
        for (int nt = 0; nt < 4; ++nt) { accP[ht][nt] = (floatx4)0.f; accQ[ht][nt] = (floatx4)0.f; }

    #pragma unroll
    for (int ks = 0; ks < 2; ++ks) {
        half8 aH[2], aL[2], bH[4], bL[4];
        #pragma unroll
        for (int ht = 0; ht < 2; ++ht) {
            const int off = (wave * 32 + ht * 16 + c) * W1_KP + ks * 32 + q * 8;
            aH[ht] = *(const half8*)(smem + L_W1HI + off * 2);
            aL[ht] = *(const half8*)(smem + L_W1LO + off * 2);
        }
        #pragma unroll
        for (int nt = 0; nt < 4; ++nt) {
            const int off = (nt * 16 + c + ks) * XS_ROW + q * 8;  // window overlap trick
            bH[nt] = *(const half8*)(smem + L_XSHI + off * 2);
            bL[nt] = *(const half8*)(smem + L_XSLO + off * 2);
        }
        #pragma unroll
        for (int ht = 0; ht < 2; ++ht)
            #pragma unroll
            for (int nt = 0; nt < 4; ++nt) {
                accP[ht][nt] = __builtin_amdgcn_mfma_f32_16x16x32_f16(aH[ht], bH[nt], accP[ht][nt], 0, 0, 0);
                accQ[ht][nt] = __builtin_amdgcn_mfma_f32_16x16x32_f16(aH[ht], bL[nt], accQ[ht][nt], 0, 0, 0);
                accQ[ht][nt] = __builtin_amdgcn_mfma_f32_16x16x32_f16(aL[ht], bH[nt], accQ[ht][nt], 0, 0, 0);
            }
    }
    __syncthreads();   // phase-1 LDS reads done; gb/w1T overlay is now safe

    // ---------- epilogue: pre -> g (LDS, A-layout), res/jac64 partials; stage w1T ----------
    {
        const float4* s = (const float4*)(ws + WS_W1T + (size_t)d * 17408);
        float4* dst = (float4*)(smem + L_W1T);
        for (int i = tid; i < 1088; i += 256) dst[i] = s[i];
    }
    float res[4] = {0.f, 0.f, 0.f, 0.f}, j64[4] = {0.f, 0.f, 0.f, 0.f};
    #pragma unroll
    for (int ht = 0; ht < 2; ++ht) {
        const int hbase = wave * 32 + ht * 16 + q * 4;   // D row = q*4 + reg
        #pragma unroll
        for (int nt = 0; nt < 4; ++nt) {
            const int n = nt * 16 + c;                   // D col = lane&15
            half4 gp;
            #pragma unroll
            for (int r = 0; r < 4; ++r) {
                const int h = hbase + r;
                const float pre = accP[ht][nt][r] + accQ[ht][nt][r] * (1.0f / 4096.0f)
                                + b1L[h] + yyL[n] * w64L[h];
                const float gg = (pre >= 0.f ? 1.0f : 0.01f) * W2L[h];
                res[nt] += pre * gg;
                j64[nt] += gg * w64L[h];
                gp[r] = (f16)gg;
            }
            *(half4*)(smem + L_GB + (n * W1T_HP + hbase) * 2) = gp;
        }
    }
    #pragma unroll
    for (int nt = 0; nt < 4; ++nt) {
        float rv = res[nt];
        rv += __shfl_xor(rv, 16, 64);
        rv += __shfl_xor(rv, 32, 64);
        float jv = j64[nt];
        jv += __shfl_xor(jv, 16, 64);
        jv += __shfl_xor(jv, 32, 64);
        if (lane < 16) {
            resP[wave * 64 + nt * 16 + lane] = rv;
            jacP[wave * 64 + nt * 16 + lane] = jv;
        }
    }
    __syncthreads();

    // ---------- residuals + logabsdet (one wave) ----------
    if (tid < 64) {
        const int n = tid;
        float r = b2[d], j = 0.f;
        #pragma unroll
        for (int w = 0; w < 4; ++w) { r += resP[w * 64 + n]; j += jacP[w * 64 + n]; }
        out[(size_t)(b * 512 + t0 + n) * 32 + d] = r;
        float lg = logf(fabsf(j));
        #pragma unroll
        for (int off = 32; off > 0; off >>= 1) lg += __shfl_down(lg, off, 64);
        if (tid == 0) atomicAdd(out + OUT1_OFF + b, lg);
    }

    // ---------- phase 2: jac[n, k<64] = g . W1 ; wave owns one 16-n tile ----------
    floatx4 acc2[4];
    #pragma unroll
    for (int kt = 0; kt < 4; ++kt) acc2[kt] = (floatx4)0.f;
    #pragma unroll
    for (int ks = 0; ks < 4; ++ks) {
        const half8 aF = *(const half8*)(smem + L_GB + ((wave * 16 + c) * W1T_HP + ks * 32 + q * 8) * 2);
        half8 bF[4];
        #pragma unroll
        for (int kt = 0; kt < 4; ++kt)
            bF[kt] = *(const half8*)(smem + L_W1T + ((kt * 16 + c) * W1T_HP + ks * 32 + q * 8) * 2);
        #pragma unroll
        for (int kt = 0; kt < 4; ++kt)
            acc2[kt] = __builtin_amdgcn_mfma_f32_16x16x32_f16(aF, bF[kt], acc2[kt], 0, 0, 0);
    }
    {
        float* out2 = out + OUT2_OFF + (size_t)d * ((size_t)32768 * 64)
                    + (size_t)(b * 512 + t0) * 64;
        #pragma unroll
        for (int kt = 0; kt < 4; ++kt)
            #pragma unroll
            for (int r = 0; r < 4; ++r)
                out2[(size_t)(wave * 16 + q * 4 + r) * 64 + kt * 16 + c] = acc2[kt][r];
    }
}

extern "C" void kernel_launch(void* const* d_in, const int* in_sizes, int n_in,
                              void* d_out, int out_size, void* d_ws, size_t ws_size,
                              hipStream_t stream) {
    const float* x  = (const float*)d_in[0];
    const float* W1 = (const float*)d_in[1];
    const float* b1 = (const float*)d_in[2];
    const float* W2 = (const float*)d_in[3];
    const float* b2 = (const float*)d_in[4];
    float* out = (float*)d_out;
    char* ws = (char*)d_ws;

    hipMemsetAsync(out + OUT1_OFF, 0, 64 * sizeof(float), stream);

    hipLaunchKernelGGL(split_x_kernel, dim3((64 * 514 * 32 + 255) / 256), dim3(256), 0, stream,
                       x, (f16*)(ws + WS_XS_HI), (f16*)(ws + WS_XS_LO));
    hipLaunchKernelGGL(split_w1_kernel, dim3((32 * 128 * 64 + 255) / 256), dim3(256), 0, stream,
                       W1, (f16*)(ws + WS_W1_HI), (f16*)(ws + WS_W1_LO), (f16*)(ws + WS_W1T));

    hipLaunchKernelGGL(np_main_kernel, dim3(512, 32), dim3(256), L_TOTAL, stream,
                       x, W1, b1, W2, b2, (const char*)ws, out);
}